// Round 16
// baseline (703.951 us; speedup 1.0000x reference)
//
#include <hip/hip_runtime.h>
#include <hip/hip_bf16.h>

#define NTOK 1024
#define HDIM 2880
#define IDIM 2880
#define NEXP 8
#define BK 64
#define NT 45  // HDIM/BK

typedef __attribute__((ext_vector_type(4))) float fx4;
typedef __attribute__((ext_vector_type(8))) short sx8;
typedef __attribute__((ext_vector_type(8))) unsigned short usx8;

typedef const __attribute__((address_space(1))) void* gas_p;
typedef __attribute__((address_space(3))) void* las_p;

__device__ __forceinline__ unsigned short f2bf(float f) {
  __hip_bfloat16 b = __float2bfloat16(f);
  return __builtin_bit_cast(unsigned short, b);
}
__device__ __forceinline__ usx8 cvt8(fx4 a, fx4 b) {
  usx8 u = {f2bf(a.x), f2bf(a.y), f2bf(a.z), f2bf(a.w),
            f2bf(b.x), f2bf(b.y), f2bf(b.z), f2bf(b.w)};
  return u;
}
__device__ __forceinline__ float bf2f(unsigned short u) {
  unsigned v = ((unsigned)u) << 16;
  return __builtin_bit_cast(float, v);
}

#define MFMA16(a, b, c) __builtin_amdgcn_mfma_f32_16x16x32_bf16(a, b, c, 0, 0, 0)

__global__ __launch_bounds__(256) void rms_router_k(
    const float* __restrict__ x, const float* __restrict__ norm_w,
    const float* __restrict__ gate_w, const float* __restrict__ gate_b,
    unsigned short* __restrict__ t_bf, int* __restrict__ cnt,
    int* __restrict__ tok, int* __restrict__ tokE, int* __restrict__ tokS,
    float* __restrict__ tokW) {
  const int n = blockIdx.x;
  const int tid = threadIdx.x;
  const int wid = tid >> 6, lane = tid & 63;
  const float* xr = x + (size_t)n * HDIM;

  float ss = 0.f;
  for (int h = tid; h < HDIM; h += 256) { float v = xr[h]; ss += v * v; }
  #pragma unroll
  for (int o = 32; o > 0; o >>= 1) ss += __shfl_down(ss, o);
  __shared__ float sred[4];
  if (lane == 0) sred[wid] = ss;
  __syncthreads();
  const float rstd =
      rsqrtf((sred[0] + sred[1] + sred[2] + sred[3]) * (1.0f / HDIM) + 1e-5f);

  float p[NEXP];
  #pragma unroll
  for (int e = 0; e < NEXP; e++) p[e] = 0.f;
  for (int h = tid; h < HDIM; h += 256) {
    float xv = xr[h] * norm_w[h];
    t_bf[(size_t)n * HDIM + h] = f2bf(xv * rstd);
    #pragma unroll
    for (int e = 0; e < NEXP; e++) p[e] += xv * gate_w[e * HDIM + h];
  }
  __shared__ float pls[4][NEXP];
  #pragma unroll
  for (int e = 0; e < NEXP; e++) {
    float v = p[e];
    #pragma unroll
    for (int o = 32; o > 0; o >>= 1) v += __shfl_down(v, o);
    if (lane == 0) pls[wid][e] = v;
  }
  __syncthreads();
  if (tid == 0) {
    float lg[NEXP];
    #pragma unroll
    for (int e = 0; e < NEXP; e++)
      lg[e] = (pls[0][e] + pls[1][e] + pls[2][e] + pls[3][e]) * rstd + gate_b[e];
    unsigned used = 0;
    float val[4];
    int idx[4];
    for (int k = 0; k < 4; k++) {
      float best = -1e30f;
      int bi = 0;
      for (int e = 0; e < NEXP; e++)
        if (!((used >> e) & 1u) && lg[e] > best) { best = lg[e]; bi = e; }
      used |= 1u << bi;
      val[k] = best;
      idx[k] = bi;
    }
    float sum = 0.f, w[4];
    for (int k = 0; k < 4; k++) { w[k] = expf(val[k] - val[0]); sum += w[k]; }
    for (int k = 0; k < 4; k++) {
      int e = idx[k];
      int slot = atomicAdd(&cnt[e], 1);
      tok[e * NTOK + slot] = n;
      tokE[n * 4 + k] = e;
      tokS[n * 4 + k] = slot;
      tokW[n * 4 + k] = w[k] / sum;
    }
  }
}

// Dense-pack gathered token rows; zero-fill to 128-boundary.
__global__ __launch_bounds__(256) void pack_k(
    const unsigned short* __restrict__ t_bf, const int* __restrict__ cnt,
    const int* __restrict__ tok, unsigned short* __restrict__ a_pack) {
  const int e = blockIdx.x >> 8;
  const int r0 = (blockIdx.x & 255) * 4;
  const int ce = cnt[e];
  const int lim = (ce + 127) & ~127;
  if (r0 >= lim) return;
  const int row = r0 + (threadIdx.x >> 6);
  const int lane = threadIdx.x & 63;
  unsigned short* dst = a_pack + ((size_t)e * NTOK + row) * HDIM;
  if (row < ce) {
    const unsigned short* src = t_bf + (size_t)tok[e * NTOK + row] * HDIM;
    for (int c = lane; c < HDIM / 8; c += 64)
      *(usx8*)(dst + c * 8) = *(const usx8*)(src + c * 8);
  } else {
    const usx8 z = {0, 0, 0, 0, 0, 0, 0, 0};
    for (int c = lane; c < HDIM / 8; c += 64) *(usx8*)(dst + c * 8) = z;
  }
}

// GEMM1: BM=256 x 64 I-cols x {G,L}, BK=64, 8 waves (4m x 2n), full dbuf
// (A 2x32KB gload_lds + B 2x16KB reg-cvt), T3-min pipeline: ONE barrier/tile,
// staging issued a full compute-phase ahead, drain is tile-old (cheap).
__global__ __launch_bounds__(512, 1) void gemm1_k(
    const unsigned short* __restrict__ a_pack,
    const float* __restrict__ w_gate_up, const float* __restrict__ b_gate_up,
    const int* __restrict__ cnt, unsigned short* __restrict__ act_bf) {
  const int h = blockIdx.x;
  const int s = h / 3, z = h - s * 3;  // twins adjacent -> B L3-shared
  const int e = s / 45;
  const int c0 = (s % 45) * 64;
  const int m0 = z * 256;
  const int ce = cnt[e];
  if (m0 >= ce) return;

  const int tid = threadIdx.x, lane = tid & 63, wid = tid >> 6;
  const int fr = lane & 15, fq = lane >> 4;
  const int wm = wid >> 1, wn = wid & 1;
  const int sw = ((lane & 7) ^ ((lane >> 3) & 7)) * 8;

  __shared__ __align__(16) unsigned short Ash[2][256 * 64];  // 64 KB
  __shared__ __align__(16) unsigned short Bsh[2][128 * 64];  // 32 KB (G:0-63 L:64-127)

  const fx4 FZ = {0.f, 0.f, 0.f, 0.f};
  fx4 accG[4][2], accL[4][2];
  #pragma unroll
  for (int m = 0; m < 4; m++)
    #pragma unroll
    for (int n = 0; n < 2; n++) { accG[m][n] = FZ; accL[m][n] = FZ; }

  // A: dense rows; per wave 4 DMA x 8 rows (wave covers wid*32..+31).
  const unsigned short* gA[4];
  #pragma unroll
  for (int j = 0; j < 4; ++j) {
    int row = m0 + wid * 32 + j * 8 + (lane >> 3);
    gA[j] = a_pack + ((size_t)e * NTOK + row) * HDIM + sw;
  }
  // B: 128 rows (64 G + 64 L) x 8 chunks = 1024 slots; 2 slots/thread.
  const float* fB[2];
  int bO[2];
  #pragma unroll
  for (int q = 0; q < 2; ++q) {
    int sl = tid + 512 * q;
    int bR = sl >> 3, bC = sl & 7;
    int wr = bR < 64 ? (c0 + bR) : (IDIM + c0 + (bR - 64));
    fB[q] = w_gate_up + ((size_t)e * (2 * IDIM) + wr) * HDIM + bC * 8;
    bO[q] = bR * 64 + ((bC ^ (bR & 7)) * 8);
  }

  fx4 Ra[4];
  #define G1_DMA_A(kt, bb)                                                     \
    {                                                                          \
      _Pragma("unroll") for (int j = 0; j < 4; ++j)                            \
          __builtin_amdgcn_global_load_lds(                                    \
              (gas_p)(gA[j] + (size_t)(kt)*BK),                                \
              (las_p)&Ash[bb][(wid * 32 + j * 8) * 64], 16, 0, 0);             \
    }
  #define G1_LOADB(kt)                                                         \
    {                                                                          \
      _Pragma("unroll") for (int q = 0; q < 2; ++q) {                          \
        Ra[2 * q] = *(const fx4*)(fB[q] + (size_t)(kt)*BK);                    \
        Ra[2 * q + 1] = *(const fx4*)(fB[q] + (size_t)(kt)*BK + 4);            \
      }                                                                        \
    }
  #define G1_WRITEB(bb)                                                        \
    {                                                                          \
      _Pragma("unroll") for (int q = 0; q < 2; ++q)                            \
          *(usx8*)&Bsh[bb][bO[q]] = cvt8(Ra[2 * q], Ra[2 * q + 1]);            \
    }
  #define G1_COMPUTE(bb)                                                       \
    {                                                                          \
      _Pragma("unroll") for (int ks = 0; ks < 2; ++ks) {                       \
        const int off = ((ks * 4 + fq) ^ (fr & 7)) * 8;                        \
        sx8 aF[4], bG[2], bL[2];                                               \
        _Pragma("unroll") for (int m = 0; m < 4; ++m) aF[m] =                  \
            *(const sx8*)&Ash[bb][(wm * 64 + m * 16 + fr) * 64 + off];         \
        _Pragma("unroll") for (int n = 0; n < 2; ++n) {                        \
          bG[n] = *(const sx8*)&Bsh[bb][(wn * 32 + n * 16 + fr) * 64 + off];   \
          bL[n] =                                                              \
              *(const sx8*)&Bsh[bb][(64 + wn * 32 + n * 16 + fr) * 64 + off];  \
        }                                                                      \
        __builtin_amdgcn_s_setprio(1);                                         \
        _Pragma("unroll") for (int n = 0; n < 2; ++n)                          \
            _Pragma("unroll") for (int m = 0; m < 4; ++m) {                    \
          accG[m][n] = MFMA16(aF[m], bG[n], accG[m][n]);                       \
          accL[m][n] = MFMA16(aF[m], bL[n], accL[m][n]);                       \
        }                                                                      \
        __builtin_amdgcn_s_setprio(0);                                         \
      }                                                                        \
    }

  // prologue: tile0 fully staged; tile1 in flight
  G1_DMA_A(0, 0);
  G1_LOADB(0);
  G1_WRITEB(0);
  G1_DMA_A(1, 1);
  G1_LOADB(1);
  __syncthreads();  // startup drain (once)

  int cur = 0;
  for (int t = 0; t < NT; ++t) {
    G1_COMPUTE(cur);
    if (t + 1 < NT) G1_WRITEB(cur ^ 1);  // Ra holds B(t+1); loads are old
    __syncthreads();  // drains tile-old loads; nxt ready; cur freed
    if (t + 2 < NT) {
      G1_DMA_A(t + 2, cur);  // into freed buf; flies under next compute
      G1_LOADB(t + 2);
    }
    cur ^= 1;
  }

  #pragma unroll
  for (int n = 0; n < 2; ++n) {
    const int col = c0 + wn * 32 + n * 16 + fr;
    const float bg = b_gate_up[e * (2 * IDIM) + col];
    const float bl = b_gate_up[e * (2 * IDIM) + IDIM + col];
    #pragma unroll
    for (int m = 0; m < 4; ++m) {
      #pragma unroll
      for (int r = 0; r < 4; ++r) {
        int slot = m0 + wm * 64 + m * 16 + fq * 4 + r;
        if (slot < ce) {
          float gv = accG[m][n][r] + bg;
          float lv = accL[m][n][r] + bl;
          float a = gv * (1.0f / (1.0f + __expf(-1.702f * gv))) * (lv + 1.0f);
          act_bf[((size_t)e * NTOK + slot) * IDIM + col] = f2bf(a);
        }
      }
    }
  }
}

// GEMM2: BM=256 x 96 cols, BK=64, 8 waves (4m x 2n), same pipeline.
// Writes outs_bf densely (no atomics).
__global__ __launch_bounds__(512, 1) void gemm2_k(
    const unsigned short* __restrict__ act_bf, const float* __restrict__ w_down,
    const float* __restrict__ b_down, const int* __restrict__ cnt,
    unsigned short* __restrict__ outs_bf) {
  const int h = blockIdx.x;
  const int s = h / 3, z = h - s * 3;
  const int e = s / 30;
  const int c0 = (s % 30) * 96;
  const int m0 = z * 256;
  const int ce = cnt[e];
  if (m0 >= ce) return;

  const int tid = threadIdx.x, lane = tid & 63, wid = tid >> 6;
  const int fr = lane & 15, fq = lane >> 4;
  const int wm = wid >> 1, wn = wid & 1;
  const int sw = ((lane & 7) ^ ((lane >> 3) & 7)) * 8;

  __shared__ __align__(16) unsigned short Ash[2][256 * 64];  // 64 KB
  __shared__ __align__(16) unsigned short Bsh[2][96 * 64];   // 24 KB

  const fx4 FZ = {0.f, 0.f, 0.f, 0.f};
  fx4 acc[4][3];
  #pragma unroll
  for (int m = 0; m < 4; m++)
    #pragma unroll
    for (int n = 0; n < 3; n++) acc[m][n] = FZ;

  const unsigned short* gA[4];
  #pragma unroll
  for (int j = 0; j < 4; ++j) {
    int row = m0 + wid * 32 + j * 8 + (lane >> 3);
    gA[j] = act_bf + ((size_t)e * NTOK + row) * IDIM + sw;
  }
  // B: 96 rows x 8 chunks = 768 slots; slot tid, plus tid+512 for tid<256.
  const int bR0 = tid >> 3, bC0 = tid & 7;
  const int s1 = tid + 512;
  const int bR1 = s1 >> 3, bC1 = s1 & 7;
  const float* wb = w_down + (size_t)e * HDIM * IDIM;
  const float* fB0 = wb + (size_t)(c0 + bR0) * IDIM + bC0 * 8;
  const float* fB1 = wb + (size_t)(c0 + bR1) * IDIM + bC1 * 8;
  const int bO0 = bR0 * 64 + ((bC0 ^ (bR0 & 7)) * 8);
  const int bO1 = bR1 * 64 + ((bC1 ^ (bR1 & 7)) * 8);

  fx4 Ra[4];
  #define G2_DMA_A(kt, bb)                                                     \
    {                                                                          \
      _Pragma("unroll") for (int j = 0; j < 4; ++j)                            \
          __builtin_amdgcn_global_load_lds(                                    \
              (gas_p)(gA[j] + (size_t)(kt)*BK),                                \
              (las_p)&Ash[bb][(wid * 32 + j * 8) * 64], 16, 0, 0);             \
    }
  #define G2_LOADB(kt)                                                         \
    {                                                                          \
      Ra[0] = *(const fx4*)(fB0 + (size_t)(kt)*BK);                            \
      Ra[1] = *(const fx4*)(fB0 + (size_t)(kt)*BK + 4);                        \
      if (tid < 256) {                                                         \
        Ra[2] = *(const fx4*)(fB1 + (size_t)(kt)*BK);                          \
        Ra[3] = *(const fx4*)(fB1 + (size_t)(kt)*BK + 4);                      \
      }                                                                        \
    }
  #define G2_WRITEB(bb)                                                        \
    {                                                                          \
      *(usx8*)&Bsh[bb][bO0] = cvt8(Ra[0], Ra[1]);                              \
      if (tid < 256) *(usx8*)&Bsh[bb][bO1] = cvt8(Ra[2], Ra[3]);               \
    }
  #define G2_COMPUTE(bb)                                                       \
    {                                                                          \
      _Pragma("unroll") for (int ks = 0; ks < 2; ++ks) {                       \
        const int off = ((ks * 4 + fq) ^ (fr & 7)) * 8;                        \
        sx8 aF[4], bB[3];                                                      \
        _Pragma("unroll") for (int m = 0; m < 4; ++m) aF[m] =                  \
            *(const sx8*)&Ash[bb][(wm * 64 + m * 16 + fr) * 64 + off];         \
        _Pragma("unroll") for (int n = 0; n < 3; ++n) bB[n] =                  \
            *(const sx8*)&Bsh[bb][(wn * 48 + n * 16 + fr) * 64 + off];         \
        __builtin_amdgcn_s_setprio(1);                                         \
        _Pragma("unroll") for (int n = 0; n < 3; ++n)                          \
            _Pragma("unroll") for (int m = 0; m < 4; ++m)                      \
                acc[m][n] = MFMA16(aF[m], bB[n], acc[m][n]);                   \
        __builtin_amdgcn_s_setprio(0);                                         \
      }                                                                        \
    }

  G2_DMA_A(0, 0);
  G2_LOADB(0);
  G2_WRITEB(0);
  G2_DMA_A(1, 1);
  G2_LOADB(1);
  __syncthreads();

  int cur = 0;
  for (int t = 0; t < NT; ++t) {
    G2_COMPUTE(cur);
    if (t + 1 < NT) G2_WRITEB(cur ^ 1);
    __syncthreads();
    if (t + 2 < NT) {
      G2_DMA_A(t + 2, cur);
      G2_LOADB(t + 2);
    }
    cur ^= 1;
  }

  #pragma unroll
  for (int n = 0; n < 3; ++n) {
    const int col = c0 + wn * 48 + n * 16 + fr;
    const float bias = b_down[e * HDIM + col];
    #pragma unroll
    for (int m = 0; m < 4; ++m) {
      #pragma unroll
      for (int r = 0; r < 4; ++r) {
        int slot = m0 + wm * 64 + m * 16 + fq * 4 + r;
        if (slot < ce)
          outs_bf[((size_t)e * NTOK + slot) * HDIM + col] =
              f2bf(acc[m][n][r] + bias);
      }
    }
  }
}

// combine: out[n] = x[n] + sum_k w_k * outs_bf[e_k, s_k]
__global__ __launch_bounds__(256) void combine_k(
    const float* __restrict__ x, const unsigned short* __restrict__ outs_bf,
    const int* __restrict__ tokE, const int* __restrict__ tokS,
    const float* __restrict__ tokW, float* __restrict__ out) {
  const int n = blockIdx.x;
  const unsigned short* src[4];
  float w[4];
  #pragma unroll
  for (int k = 0; k < 4; ++k) {
    int e = tokE[n * 4 + k], s = tokS[n * 4 + k];
    w[k] = tokW[n * 4 + k];
    src[k] = outs_bf + ((size_t)e * NTOK + s) * HDIM;
  }
  const float* xr = x + (size_t)n * HDIM;
  float* orow = out + (size_t)n * HDIM;
  for (int c = threadIdx.x; c < HDIM / 8; c += 256) {
    fx4 lo = *(const fx4*)(xr + c * 8);
    fx4 hi = *(const fx4*)(xr + c * 8 + 4);
    #pragma unroll
    for (int k = 0; k < 4; ++k) {
      usx8 v = *(const usx8*)(src[k] + c * 8);
      lo.x += w[k] * bf2f(v[0]);
      lo.y += w[k] * bf2f(v[1]);
      lo.z += w[k] * bf2f(v[2]);
      lo.w += w[k] * bf2f(v[3]);
      hi.x += w[k] * bf2f(v[4]);
      hi.y += w[k] * bf2f(v[5]);
      hi.z += w[k] * bf2f(v[6]);
      hi.w += w[k] * bf2f(v[7]);
    }
    *(fx4*)(orow + c * 8) = lo;
    *(fx4*)(orow + c * 8 + 4) = hi;
  }
}

extern "C" void kernel_launch(void* const* d_in, const int* in_sizes, int n_in,
                              void* d_out, int out_size, void* d_ws,
                              size_t ws_size, hipStream_t stream) {
  const float* x = (const float*)d_in[0];
  const float* norm_w = (const float*)d_in[1];
  const float* gate_w = (const float*)d_in[2];
  const float* gate_b = (const float*)d_in[3];
  const float* w_gate_up = (const float*)d_in[4];
  const float* b_gate_up = (const float*)d_in[5];
  const float* w_down = (const float*)d_in[6];
  const float* b_down = (const float*)d_in[7];
  float* out = (float*)d_out;

  char* ws = (char*)d_ws;
  size_t off = 0;
  unsigned short* t_bf = (unsigned short*)(ws + off);
  off += (size_t)NTOK * HDIM * 2;
  unsigned short* a_pack = (unsigned short*)(ws + off);
  off += (size_t)NEXP * NTOK * HDIM * 2;
  unsigned short* act_bf = (unsigned short*)(ws + off);
  off += (size_t)NEXP * NTOK * IDIM * 2;
  unsigned short* outs_bf = (unsigned short*)(ws + off);
  off += (size_t)NEXP * NTOK * HDIM * 2;
  int* cnt = (int*)(ws + off);
  off += 256;
  int* tok = (int*)(ws + off);
  off += (size_t)NEXP * NTOK * 4;
  int* tokE = (int*)(ws + off);
  off += (size_t)NTOK * 4 * 4;
  int* tokS = (int*)(ws + off);
  off += (size_t)NTOK * 4 * 4;
  float* tokW = (float*)(ws + off);
  off += (size_t)NTOK * 4 * 4;

  hipMemsetAsync(cnt, 0, NEXP * sizeof(int), stream);
  rms_router_k<<<NTOK, 256, 0, stream>>>(x, norm_w, gate_w, gate_b, t_bf, cnt,
                                         tok, tokE, tokS, tokW);
  pack_k<<<NEXP * 256, 256, 0, stream>>>(t_bf, cnt, tok, a_pack);
  // h = s*3 + z: the 3 row-tile twins of each (e,c)-slice are CONSECUTIVE
  // blocks (co-resident) -> B panel fetched from HBM once, L3-shared.
  gemm1_k<<<360 * 3, 512, 0, stream>>>(a_pack, w_gate_up, b_gate_up, cnt,
                                       act_bf);
  gemm2_k<<<240 * 3, 512, 0, stream>>>(act_bf, w_down, b_down, cnt, outs_bf);
  combine_k<<<NTOK, 256, 0, stream>>>(x, outs_bf, tokE, tokS, tokW, out);
}